// Round 3
// baseline (20241.989 us; speedup 1.0000x reference)
//
#include <hip/hip_runtime.h>
#include <hip/hip_bf16.h>
#include <math.h>

typedef __hip_bfloat16 bf16;

#define BB 8
#define CC 96
#define HH 224
#define WW 224
#define HWPIX (HH*WW)
#define TOK 49          // 7*7 tokens per window
#define NWIN 1024       // windows per image
#define NTOK (BB*HH*WW) // 401408 tokens

__device__ __forceinline__ float b2f(bf16 v){ return __bfloat162float(v); }
__device__ __forceinline__ bf16  f2b(float v){ return __float2bfloat16(v); }

// ---------------- transpose kernels (fast path only) ----------------
__global__ __launch_bounds__(256) void k_nchw2nhwc(const float* __restrict__ x,
                                                   float* __restrict__ hbuf, int n) {
    int i = blockIdx.x * 256 + threadIdx.x;
    if (i >= n) return;
    int w = i % WW;
    int t = i / WW;
    int h = t % HH; t /= HH;
    int c = t % CC;
    int b = t / CC;
    hbuf[((b*HH + h)*WW + w)*CC + c] = x[i];
}

__global__ __launch_bounds__(256) void k_nhwc2nchw(const float* __restrict__ hbuf,
                                                   float* __restrict__ out, int n) {
    int i = blockIdx.x * 256 + threadIdx.x;
    if (i >= n) return;
    int w = i % WW;
    int t = i / WW;
    int h = t % HH; t /= HH;
    int c = t % CC;
    int b = t / CC;
    out[i] = hbuf[((b*HH + h)*WW + w)*CC + c];
}

// ---------------- Kernel A: shifted-window attention + residual ----------
// one block (256 thr) per window; 8192 blocks.
// Layout-parametrized: element (b, h, w, c) lives at  b*sB + h*sH + w*sW + c*sC
// in both inbuf (residual source) and outbuf (h1 destination). inbuf may
// equal outbuf (in-place): blocks touch disjoint token sets.
__global__ __launch_bounds__(256) void k_attn(const float* __restrict__ inbuf,
                                              float* __restrict__ outbuf,
                                              const float* __restrict__ n1w,
                                              const float* __restrict__ n1b,
                                              const float* __restrict__ qkv_w,
                                              const float* __restrict__ qkv_b,
                                              const float* __restrict__ rel_table,
                                              const float* __restrict__ proj_w,
                                              const float* __restrict__ proj_b,
                                              int sB, int sH, int sW, int sC) {
    __shared__ float lnbuf[TOK][CC];        // LN1 values, later reused for attn@V
    __shared__ bf16  qs[TOK][CC];
    __shared__ bf16  ks[TOK][CC];
    __shared__ bf16  vs[TOK][CC];
    __shared__ float attn[TOK][TOK];
    __shared__ int   gbase[TOK];
    __shared__ int   lab[TOK];

    const int tid  = threadIdx.x;
    const int lane = tid & 63;
    const int wv   = tid >> 6;              // 4 waves

    const int gi = blockIdx.x;
    const int b  = gi >> 10;
    const int wrem = gi & 1023;
    const int wy = wrem >> 5;
    const int wx = wrem & 31;

    // ---- stage 1: gather (with cyclic shift) + LayerNorm1 ----
    for (int t = wv; t < TOK; t += 4) {
        int ty = t / 7, tx = t % 7;
        int hr = wy*7 + ty, wr = wx*7 + tx;      // rolled coords
        int sh = hr + 3; if (sh >= HH) sh -= HH; // source coords in original image
        int sw = wr + 3; if (sw >= WW) sw -= WW;
        int base = b*sB + sh*sH + sw*sW;
        if (lane == 0) {
            gbase[t] = base;
            int rl = hr < (HH-7) ? 0 : (hr < (HH-3) ? 1 : 2);
            int cl = wr < (WW-7) ? 0 : (wr < (WW-3) ? 1 : 2);
            lab[t] = rl*3 + cl;
        }
        float v0 = inbuf[base + lane*sC];
        float v1 = (lane < 32) ? inbuf[base + (64 + lane)*sC] : 0.f;
        float s  = v0 + v1;
        float s2 = v0*v0 + v1*v1;
        #pragma unroll
        for (int off = 32; off; off >>= 1) {
            s  += __shfl_down(s,  off, 64);
            s2 += __shfl_down(s2, off, 64);
        }
        s  = __shfl(s, 0, 64);
        s2 = __shfl(s2, 0, 64);
        float mu  = s * (1.f/96.f);
        float var = s2 * (1.f/96.f) - mu*mu;
        float rs  = rsqrtf(var + 1e-5f);
        lnbuf[t][lane] = (v0 - mu)*rs*n1w[lane] + n1b[lane];
        if (lane < 32)
            lnbuf[t][64+lane] = (v1 - mu)*rs*n1w[64+lane] + n1b[64+lane];
    }
    __syncthreads();

    // ---- stage 2: QKV = LN1 @ W^T + b ----
    const float qscale = 0.10206207261596577f; // 96^-0.5
    for (int o = tid; o < TOK*288; o += 256) {
        int t = o / 288, j = o % 288;
        const float* wrow = qkv_w + j*CC;
        float acc = qkv_b[j];
        #pragma unroll 8
        for (int c = 0; c < CC; ++c) acc += lnbuf[t][c] * wrow[c];
        if (j < 96)        qs[t][j]      = f2b(acc * qscale);
        else if (j < 192)  ks[t][j-96]   = f2b(acc);
        else               vs[t][j-192]  = f2b(acc);
    }
    __syncthreads();

    // ---- stage 3: scores + rel-pos bias + shift mask ----
    for (int p = tid; p < TOK*TOK; p += 256) {
        int qt = p / TOK, kt = p % TOK;
        float acc = 0.f;
        #pragma unroll 8
        for (int c = 0; c < CC; ++c) acc += b2f(qs[qt][c]) * b2f(ks[kt][c]);
        int dy = qt/7 - kt/7 + 6;
        int dx = qt%7 - kt%7 + 6;
        acc += rel_table[dy*13 + dx];
        if (lab[qt] != lab[kt]) acc -= 100.f;
        attn[qt][kt] = acc;
    }
    __syncthreads();

    // ---- stage 4: softmax per query row ----
    for (int t = wv; t < TOK; t += 4) {
        float x = (lane < TOK) ? attn[t][lane] : -1e30f;
        float m = x;
        #pragma unroll
        for (int off = 32; off; off >>= 1) m = fmaxf(m, __shfl_down(m, off, 64));
        m = __shfl(m, 0, 64);
        float e = (lane < TOK) ? expf(x - m) : 0.f;
        float s = e;
        #pragma unroll
        for (int off = 32; off; off >>= 1) s += __shfl_down(s, off, 64);
        s = __shfl(s, 0, 64);
        if (lane < TOK) attn[t][lane] = e / s;
    }
    __syncthreads();

    // ---- stage 5: attn @ V  (into lnbuf, LN1 no longer needed) ----
    for (int o = tid; o < TOK*CC; o += 256) {
        int t = o / CC, c = o % CC;
        float acc = 0.f;
        #pragma unroll 7
        for (int k = 0; k < TOK; ++k) acc += attn[t][k] * b2f(vs[k][c]);
        lnbuf[t][c] = acc;
    }
    __syncthreads();

    // ---- stage 6: proj + residual ----
    for (int o = tid; o < TOK*CC; o += 256) {
        int t = o / CC, c = o % CC;
        const float* pw = proj_w + c*CC;
        float acc = proj_b[c];
        #pragma unroll 8
        for (int d = 0; d < CC; ++d) acc += lnbuf[t][d] * pw[d];
        int g = gbase[t] + c*sC;
        outbuf[g] = inbuf[g] + acc;
    }
}

// ---------------- Kernel B: LN2 + MLP + residual, in place -----------------
// 4 tokens per block (one per wave). token tok -> base = (tok/HWPIX)*sB +
// (tok%HWPIX)*sPix, channel c at base + c*sC. In-place safe per token-block.
__global__ __launch_bounds__(256) void k_mlp(float* __restrict__ buf,
                                             const float* __restrict__ n2w,
                                             const float* __restrict__ n2b,
                                             const float* __restrict__ w1,
                                             const float* __restrict__ b1,
                                             const float* __restrict__ w2,
                                             const float* __restrict__ b2,
                                             int sB, int sPix, int sC) {
    __shared__ float ln2[4][CC];
    __shared__ float hid[4][384];
    __shared__ float hraw[4][CC];
    __shared__ int   tbase[4];

    const int tid  = threadIdx.x;
    const int lane = tid & 63;
    const int wv   = tid >> 6;
    const int tok0 = blockIdx.x * 4;

    // ---- LN2 (wave per token) ----
    {
        int tok = tok0 + wv;
        int base = (tok / HWPIX)*sB + (tok % HWPIX)*sPix;
        if (lane == 0) tbase[wv] = base;
        float v0 = buf[base + lane*sC];
        float v1 = (lane < 32) ? buf[base + (64 + lane)*sC] : 0.f;
        float s  = v0 + v1;
        float s2 = v0*v0 + v1*v1;
        #pragma unroll
        for (int off = 32; off; off >>= 1) {
            s  += __shfl_down(s,  off, 64);
            s2 += __shfl_down(s2, off, 64);
        }
        s  = __shfl(s, 0, 64);
        s2 = __shfl(s2, 0, 64);
        float mu  = s * (1.f/96.f);
        float var = s2 * (1.f/96.f) - mu*mu;
        float rs  = rsqrtf(var + 1e-5f);
        hraw[wv][lane] = v0;
        ln2[wv][lane]  = (v0 - mu)*rs*n2w[lane] + n2b[lane];
        if (lane < 32) {
            hraw[wv][64+lane] = v1;
            ln2[wv][64+lane]  = (v1 - mu)*rs*n2w[64+lane] + n2b[64+lane];
        }
    }
    __syncthreads();

    // ---- hidden = GELU(ln2 @ w1^T + b1) ----
    for (int o = tid; o < 4*384; o += 256) {
        int ti = o / 384, j = o % 384;
        const float* wrow = w1 + j*CC;
        float acc = b1[j];
        #pragma unroll 8
        for (int c = 0; c < CC; ++c) acc += ln2[ti][c] * wrow[c];
        hid[ti][j] = 0.5f * acc * (1.f + erff(acc * 0.70710678118654752f));
    }
    __syncthreads();

    // ---- out = hidden @ w2^T + b2, + residual (in place) ----
    for (int o = tid; o < 4*CC; o += 256) {
        int ti = o / CC, c = o % CC;
        const float* wrow = w2 + c*384;
        float acc = b2[c];
        #pragma unroll 8
        for (int k = 0; k < 384; ++k) acc += hid[ti][k] * wrow[k];
        buf[tbase[ti] + c*sC] = hraw[ti][c] + acc;
    }
}

extern "C" void kernel_launch(void* const* d_in, const int* in_sizes, int n_in,
                              void* d_out, int out_size, void* d_ws, size_t ws_size,
                              hipStream_t stream) {
    const float* x        = (const float*)d_in[0];
    const float* norm1_w  = (const float*)d_in[1];
    const float* norm1_b  = (const float*)d_in[2];
    const float* qkv_w    = (const float*)d_in[3];
    const float* qkv_b    = (const float*)d_in[4];
    const float* rel_tab  = (const float*)d_in[5];
    const float* proj_w   = (const float*)d_in[6];
    const float* proj_b   = (const float*)d_in[7];
    const float* norm2_w  = (const float*)d_in[8];
    const float* norm2_b  = (const float*)d_in[9];
    const float* mlp_w1   = (const float*)d_in[10];
    const float* mlp_b1   = (const float*)d_in[11];
    const float* mlp_w2   = (const float*)d_in[12];
    const float* mlp_b2   = (const float*)d_in[13];
    float* out = (float*)d_out;

    const int n = BB*CC*HH*WW; // 38,535,168 elements
    const size_t need = (size_t)n * sizeof(float); // 154,140,672 B

    dim3 blk(256);
    if (ws_size >= need) {
        // fast path: NHWC fp32 staging in workspace (coalesced channel reads)
        float* hbuf = (float*)d_ws;
        k_nchw2nhwc<<<dim3((n + 255)/256), blk, 0, stream>>>(x, hbuf, n);
        k_attn<<<dim3(BB*NWIN), blk, 0, stream>>>(hbuf, hbuf,
                norm1_w, norm1_b, qkv_w, qkv_b, rel_tab, proj_w, proj_b,
                HH*WW*CC, WW*CC, CC, 1);            // NHWC strides
        k_mlp<<<dim3(NTOK/4), blk, 0, stream>>>(hbuf,
                norm2_w, norm2_b, mlp_w1, mlp_b1, mlp_w2, mlp_b2,
                HH*WW*CC, CC, 1);                   // NHWC: base = tok*CC
        k_nhwc2nchw<<<dim3((n + 255)/256), blk, 0, stream>>>(hbuf, out, n);
    } else {
        // fallback: NCHW-direct, no workspace. x -> out (attn), out in-place (mlp)
        k_attn<<<dim3(BB*NWIN), blk, 0, stream>>>(x, out,
                norm1_w, norm1_b, qkv_w, qkv_b, rel_tab, proj_w, proj_b,
                CC*HH*WW, WW, 1, HH*WW);            // NCHW strides
        k_mlp<<<dim3(NTOK/4), blk, 0, stream>>>(out,
                norm2_w, norm2_b, mlp_w1, mlp_b1, mlp_w2, mlp_b2,
                CC*HH*WW, 1, HH*WW);                // NCHW: base = b*CHW + pix
    }
}

// Round 4
// 7639.415 us; speedup vs baseline: 2.6497x; 2.6497x over previous
//
#include <hip/hip_runtime.h>
#include <hip/hip_bf16.h>
#include <math.h>

typedef __hip_bfloat16 bf16;
typedef __bf16 bf16x8 __attribute__((ext_vector_type(8)));
typedef float  f32x4  __attribute__((ext_vector_type(4)));

#define BB 8
#define CC 96
#define HH 224
#define WW 224
#define HWPIX (HH*WW)
#define TOK 49          // 7*7 tokens per window
#define NWIN 1024       // windows per image
#define NTOK (BB*HH*WW) // 401408 tokens

__device__ __forceinline__ float b2f(bf16 v){ return __bfloat162float(v); }
__device__ __forceinline__ bf16  f2b(float v){ return __float2bfloat16(v); }

// ---------------- tiled transpose: NCHW -> NHWC ----------------
__global__ __launch_bounds__(256) void k_nchw2nhwc(const float* __restrict__ x,
                                                   float* __restrict__ hbuf) {
    __shared__ float tile[CC][57];  // 56-wide w tile, +1 pad
    int bid = blockIdx.x;
    int wc = bid & 3;           // 4 chunks of 56 along W
    int bh = bid >> 2;
    int h = bh % HH;
    int b = bh / HH;
    int w0 = wc * 56;
    for (int i = threadIdx.x; i < CC*56; i += 256) {
        int c = i / 56, w = i % 56;
        tile[c][w] = x[((b*CC + c)*HH + h)*WW + w0 + w];
    }
    __syncthreads();
    for (int i = threadIdx.x; i < 56*CC; i += 256) {
        int w = i / CC, c = i % CC;
        hbuf[((b*HH + h)*WW + w0 + w)*CC + c] = tile[c][w];
    }
}

// ---------------- tiled transpose: NHWC -> NCHW ----------------
__global__ __launch_bounds__(256) void k_nhwc2nchw(const float* __restrict__ hbuf,
                                                   float* __restrict__ out) {
    __shared__ float tile[CC][57];
    int bid = blockIdx.x;
    int wc = bid & 3;
    int bh = bid >> 2;
    int h = bh % HH;
    int b = bh / HH;
    int w0 = wc * 56;
    for (int i = threadIdx.x; i < 56*CC; i += 256) {
        int w = i / CC, c = i % CC;
        tile[c][w] = hbuf[((b*HH + h)*WW + w0 + w)*CC + c];
    }
    __syncthreads();
    for (int i = threadIdx.x; i < CC*56; i += 256) {
        int c = i / 56, w = i % 56;
        out[((b*CC + c)*HH + h)*WW + w0 + w] = tile[c][w];
    }
}

// ---------------- Kernel A: shifted-window attention + residual ----------
// one block (256 thr) per window; 8192 blocks. Layout-parametrized.
__global__ __launch_bounds__(256) void k_attn(const float* __restrict__ inbuf,
                                              float* __restrict__ outbuf,
                                              const float* __restrict__ n1w,
                                              const float* __restrict__ n1b,
                                              const float* __restrict__ qkv_w,
                                              const float* __restrict__ qkv_b,
                                              const float* __restrict__ rel_table,
                                              const float* __restrict__ proj_w,
                                              const float* __restrict__ proj_b,
                                              int sB, int sH, int sW, int sC) {
    __shared__ float lnbuf[TOK][CC];
    __shared__ bf16  qs[TOK][CC];
    __shared__ bf16  ks[TOK][CC];
    __shared__ bf16  vs[TOK][CC];
    __shared__ float attn[TOK][TOK];
    __shared__ int   gbase[TOK];
    __shared__ int   lab[TOK];

    const int tid  = threadIdx.x;
    const int lane = tid & 63;
    const int wv   = tid >> 6;

    const int gi = blockIdx.x;
    const int b  = gi >> 10;
    const int wrem = gi & 1023;
    const int wy = wrem >> 5;
    const int wx = wrem & 31;

    for (int t = wv; t < TOK; t += 4) {
        int ty = t / 7, tx = t % 7;
        int hr = wy*7 + ty, wr = wx*7 + tx;
        int sh = hr + 3; if (sh >= HH) sh -= HH;
        int sw = wr + 3; if (sw >= WW) sw -= WW;
        int base = b*sB + sh*sH + sw*sW;
        if (lane == 0) {
            gbase[t] = base;
            int rl = hr < (HH-7) ? 0 : (hr < (HH-3) ? 1 : 2);
            int cl = wr < (WW-7) ? 0 : (wr < (WW-3) ? 1 : 2);
            lab[t] = rl*3 + cl;
        }
        float v0 = inbuf[base + lane*sC];
        float v1 = (lane < 32) ? inbuf[base + (64 + lane)*sC] : 0.f;
        float s  = v0 + v1;
        float s2 = v0*v0 + v1*v1;
        #pragma unroll
        for (int off = 32; off; off >>= 1) {
            s  += __shfl_down(s,  off, 64);
            s2 += __shfl_down(s2, off, 64);
        }
        s  = __shfl(s, 0, 64);
        s2 = __shfl(s2, 0, 64);
        float mu  = s * (1.f/96.f);
        float var = s2 * (1.f/96.f) - mu*mu;
        float rs  = rsqrtf(var + 1e-5f);
        lnbuf[t][lane] = (v0 - mu)*rs*n1w[lane] + n1b[lane];
        if (lane < 32)
            lnbuf[t][64+lane] = (v1 - mu)*rs*n1w[64+lane] + n1b[64+lane];
    }
    __syncthreads();

    const float qscale = 0.10206207261596577f; // 96^-0.5
    for (int o = tid; o < TOK*288; o += 256) {
        int t = o / 288, j = o % 288;
        const float* wrow = qkv_w + j*CC;
        float acc = qkv_b[j];
        #pragma unroll 8
        for (int c = 0; c < CC; ++c) acc += lnbuf[t][c] * wrow[c];
        if (j < 96)        qs[t][j]      = f2b(acc * qscale);
        else if (j < 192)  ks[t][j-96]   = f2b(acc);
        else               vs[t][j-192]  = f2b(acc);
    }
    __syncthreads();

    for (int p = tid; p < TOK*TOK; p += 256) {
        int qt = p / TOK, kt = p % TOK;
        float acc = 0.f;
        #pragma unroll 8
        for (int c = 0; c < CC; ++c) acc += b2f(qs[qt][c]) * b2f(ks[kt][c]);
        int dy = qt/7 - kt/7 + 6;
        int dx = qt%7 - kt%7 + 6;
        acc += rel_table[dy*13 + dx];
        if (lab[qt] != lab[kt]) acc -= 100.f;
        attn[qt][kt] = acc;
    }
    __syncthreads();

    for (int t = wv; t < TOK; t += 4) {
        float x = (lane < TOK) ? attn[t][lane] : -1e30f;
        float m = x;
        #pragma unroll
        for (int off = 32; off; off >>= 1) m = fmaxf(m, __shfl_down(m, off, 64));
        m = __shfl(m, 0, 64);
        float e = (lane < TOK) ? expf(x - m) : 0.f;
        float s = e;
        #pragma unroll
        for (int off = 32; off; off >>= 1) s += __shfl_down(s, off, 64);
        s = __shfl(s, 0, 64);
        if (lane < TOK) attn[t][lane] = e / s;
    }
    __syncthreads();

    for (int o = tid; o < TOK*CC; o += 256) {
        int t = o / CC, c = o % CC;
        float acc = 0.f;
        #pragma unroll 7
        for (int k = 0; k < TOK; ++k) acc += attn[t][k] * b2f(vs[k][c]);
        lnbuf[t][c] = acc;
    }
    __syncthreads();

    for (int o = tid; o < TOK*CC; o += 256) {
        int t = o / CC, c = o % CC;
        const float* pw = proj_w + c*CC;
        float acc = proj_b[c];
        #pragma unroll 8
        for (int d = 0; d < CC; ++d) acc += lnbuf[t][d] * pw[d];
        int g = gbase[t] + c*sC;
        outbuf[g] = inbuf[g] + acc;
    }
}

// ---------------- Kernel B (fast path): LN2 + MLP + residual, MFMA --------
// 64 tokens per block, NHWC contiguous (token-major) layout, in place.
// GEMM1: [64x96]@W1^T -> GELU -> hidden [64x384] in 6 chunks of 64
// GEMM2: hidden @ W2^T -> [64x96], + bias + residual.
// MFMA fragment layouts (verified m89/m91): A[m=lane&15][k=quad*8+j],
// B^T[n=lane&15][k=quad*8+j], C/D col=lane&15, row=quad*4+reg.
__global__ __launch_bounds__(256) void k_mlp_mfma(float* __restrict__ buf,
                                                  const float* __restrict__ n2w,
                                                  const float* __restrict__ n2b,
                                                  const float* __restrict__ w1g,
                                                  const float* __restrict__ b1g,
                                                  const float* __restrict__ w2g,
                                                  const float* __restrict__ b2g) {
    __shared__ __bf16 sA [64][104];  // LN2(tokens) [m][k=96], pad->104 (13 dw: conflict-free)
    __shared__ __bf16 sW1[64][104];  // W1 chunk [n=64 hid][k=96]
    __shared__ __bf16 sW2[96][72];   // W2 chunk [n=96 out][k=64 hid], pad->72 (18 dw)
    __shared__ __bf16 sH [64][72];   // GELU(hidden) chunk [m=64 tok][k=64]

    const int tid  = threadIdx.x;
    const int lane = tid & 63;
    const int wv   = tid >> 6;       // 4 waves; wave wv owns token rows [16wv,16wv+16)
    const int rowm = lane & 15;
    const int quad = lane >> 4;
    const int t0   = blockIdx.x * 64;

    // ---- LN2: wave per token ----
    for (int t = wv; t < 64; t += 4) {
        int base = (t0 + t) * CC;
        float v0 = buf[base + lane];
        float v1 = (lane < 32) ? buf[base + 64 + lane] : 0.f;
        float s  = v0 + v1;
        float s2 = v0*v0 + v1*v1;
        #pragma unroll
        for (int off = 32; off; off >>= 1) {
            s  += __shfl_down(s,  off, 64);
            s2 += __shfl_down(s2, off, 64);
        }
        s  = __shfl(s, 0, 64);
        s2 = __shfl(s2, 0, 64);
        float mu  = s * (1.f/96.f);
        float var = s2 * (1.f/96.f) - mu*mu;
        float rs  = rsqrtf(var + 1e-5f);
        sA[t][lane] = (__bf16)((v0 - mu)*rs*n2w[lane] + n2b[lane]);
        if (lane < 32)
            sA[t][64+lane] = (__bf16)((v1 - mu)*rs*n2w[64+lane] + n2b[64+lane]);
    }

    f32x4 acc2[6];
    #pragma unroll
    for (int nt = 0; nt < 6; ++nt) acc2[nt] = (f32x4){0.f,0.f,0.f,0.f};

    for (int ch = 0; ch < 6; ++ch) {
        __syncthreads();  // protect sA (ch=0) and sW1/sW2/sH from prev readers
        // ---- stage W1 chunk [64 hid rows][96], W2 chunk [96 out rows][64] ----
        for (int i = tid; i < 64*96; i += 256)
            sW1[i/96][i%96] = (__bf16)w1g[ch*64*96 + i];
        for (int i = tid; i < 96*64; i += 256)
            sW2[i/64][i%64] = (__bf16)w2g[(i/64)*384 + ch*64 + (i%64)];
        __syncthreads();

        // ---- GEMM1: hidden chunk [64 tok x 64 hid] = sA @ sW1^T, GELU ----
        bf16x8 a0 = *(const bf16x8*)&sA[16*wv + rowm][ 0 + quad*8];
        bf16x8 a1 = *(const bf16x8*)&sA[16*wv + rowm][32 + quad*8];
        bf16x8 a2 = *(const bf16x8*)&sA[16*wv + rowm][64 + quad*8];
        #pragma unroll
        for (int nt = 0; nt < 4; ++nt) {
            bf16x8 w0 = *(const bf16x8*)&sW1[nt*16 + rowm][ 0 + quad*8];
            bf16x8 w1v = *(const bf16x8*)&sW1[nt*16 + rowm][32 + quad*8];
            bf16x8 w2v = *(const bf16x8*)&sW1[nt*16 + rowm][64 + quad*8];
            f32x4 acc = (f32x4){0.f,0.f,0.f,0.f};
            acc = __builtin_amdgcn_mfma_f32_16x16x32_bf16(a0, w0,  acc, 0,0,0);
            acc = __builtin_amdgcn_mfma_f32_16x16x32_bf16(a1, w1v, acc, 0,0,0);
            acc = __builtin_amdgcn_mfma_f32_16x16x32_bf16(a2, w2v, acc, 0,0,0);
            float bias = b1g[ch*64 + nt*16 + rowm];  // col n = lane&15
            #pragma unroll
            for (int r = 0; r < 4; ++r) {
                float v = acc[r] + bias;
                v = 0.5f * v * (1.f + erff(v * 0.70710678118654752f));
                sH[16*wv + quad*4 + r][nt*16 + rowm] = (__bf16)v;
            }
        }
        __syncthreads();

        // ---- GEMM2 partial: out [64 tok x 96] += sH @ sW2^T ----
        bf16x8 h0 = *(const bf16x8*)&sH[16*wv + rowm][ 0 + quad*8];
        bf16x8 h1 = *(const bf16x8*)&sH[16*wv + rowm][32 + quad*8];
        #pragma unroll
        for (int nt = 0; nt < 6; ++nt) {
            bf16x8 w0 = *(const bf16x8*)&sW2[nt*16 + rowm][ 0 + quad*8];
            bf16x8 w1v = *(const bf16x8*)&sW2[nt*16 + rowm][32 + quad*8];
            acc2[nt] = __builtin_amdgcn_mfma_f32_16x16x32_bf16(h0, w0,  acc2[nt], 0,0,0);
            acc2[nt] = __builtin_amdgcn_mfma_f32_16x16x32_bf16(h1, w1v, acc2[nt], 0,0,0);
        }
    }

    // ---- epilogue: + b2 + residual, in place ----
    #pragma unroll
    for (int nt = 0; nt < 6; ++nt) {
        int c = nt*16 + rowm;
        float bias = b2g[c];
        #pragma unroll
        for (int r = 0; r < 4; ++r) {
            int g = (t0 + 16*wv + quad*4 + r)*CC + c;
            buf[g] = buf[g] + acc2[nt][r] + bias;
        }
    }
}

// ---------------- Kernel B (fallback, strided scalar) ----------------------
__global__ __launch_bounds__(256) void k_mlp_s(float* __restrict__ buf,
                                               const float* __restrict__ n2w,
                                               const float* __restrict__ n2b,
                                               const float* __restrict__ w1,
                                               const float* __restrict__ b1,
                                               const float* __restrict__ w2,
                                               const float* __restrict__ b2,
                                               int sB, int sPix, int sC) {
    __shared__ float ln2[4][CC];
    __shared__ float hid[4][384];
    __shared__ float hraw[4][CC];
    __shared__ int   tbase[4];

    const int tid  = threadIdx.x;
    const int lane = tid & 63;
    const int wv   = tid >> 6;
    const int tok0 = blockIdx.x * 4;

    {
        int tok = tok0 + wv;
        int base = (tok / HWPIX)*sB + (tok % HWPIX)*sPix;
        if (lane == 0) tbase[wv] = base;
        float v0 = buf[base + lane*sC];
        float v1 = (lane < 32) ? buf[base + (64 + lane)*sC] : 0.f;
        float s  = v0 + v1;
        float s2 = v0*v0 + v1*v1;
        #pragma unroll
        for (int off = 32; off; off >>= 1) {
            s  += __shfl_down(s,  off, 64);
            s2 += __shfl_down(s2, off, 64);
        }
        s  = __shfl(s, 0, 64);
        s2 = __shfl(s2, 0, 64);
        float mu  = s * (1.f/96.f);
        float var = s2 * (1.f/96.f) - mu*mu;
        float rs  = rsqrtf(var + 1e-5f);
        hraw[wv][lane] = v0;
        ln2[wv][lane]  = (v0 - mu)*rs*n2w[lane] + n2b[lane];
        if (lane < 32) {
            hraw[wv][64+lane] = v1;
            ln2[wv][64+lane]  = (v1 - mu)*rs*n2w[64+lane] + n2b[64+lane];
        }
    }
    __syncthreads();

    for (int o = tid; o < 4*384; o += 256) {
        int ti = o / 384, j = o % 384;
        const float* wrow = w1 + j*CC;
        float acc = b1[j];
        #pragma unroll 8
        for (int c = 0; c < CC; ++c) acc += ln2[ti][c] * wrow[c];
        hid[ti][j] = 0.5f * acc * (1.f + erff(acc * 0.70710678118654752f));
    }
    __syncthreads();

    for (int o = tid; o < 4*CC; o += 256) {
        int ti = o / CC, c = o % CC;
        const float* wrow = w2 + c*384;
        float acc = b2[c];
        #pragma unroll 8
        for (int k = 0; k < 384; ++k) acc += hid[ti][k] * wrow[k];
        buf[tbase[ti] + c*sC] = hraw[ti][c] + acc;
    }
}

extern "C" void kernel_launch(void* const* d_in, const int* in_sizes, int n_in,
                              void* d_out, int out_size, void* d_ws, size_t ws_size,
                              hipStream_t stream) {
    const float* x        = (const float*)d_in[0];
    const float* norm1_w  = (const float*)d_in[1];
    const float* norm1_b  = (const float*)d_in[2];
    const float* qkv_w    = (const float*)d_in[3];
    const float* qkv_b    = (const float*)d_in[4];
    const float* rel_tab  = (const float*)d_in[5];
    const float* proj_w   = (const float*)d_in[6];
    const float* proj_b   = (const float*)d_in[7];
    const float* norm2_w  = (const float*)d_in[8];
    const float* norm2_b  = (const float*)d_in[9];
    const float* mlp_w1   = (const float*)d_in[10];
    const float* mlp_b1   = (const float*)d_in[11];
    const float* mlp_w2   = (const float*)d_in[12];
    const float* mlp_b2   = (const float*)d_in[13];
    float* out = (float*)d_out;

    const int n = BB*CC*HH*WW;
    const size_t need = (size_t)n * sizeof(float); // 154,140,672 B

    dim3 blk(256);
    if (ws_size >= need) {
        float* hbuf = (float*)d_ws;
        k_nchw2nhwc<<<dim3(BB*HH*4), blk, 0, stream>>>(x, hbuf);
        k_attn<<<dim3(BB*NWIN), blk, 0, stream>>>(hbuf, hbuf,
                norm1_w, norm1_b, qkv_w, qkv_b, rel_tab, proj_w, proj_b,
                HH*WW*CC, WW*CC, CC, 1);
        k_mlp_mfma<<<dim3(NTOK/64), blk, 0, stream>>>(hbuf,
                norm2_w, norm2_b, mlp_w1, mlp_b1, mlp_w2, mlp_b2);
        k_nhwc2nchw<<<dim3(BB*HH*4), blk, 0, stream>>>(hbuf, out);
    } else {
        k_attn<<<dim3(BB*NWIN), blk, 0, stream>>>(x, out,
                norm1_w, norm1_b, qkv_w, qkv_b, rel_tab, proj_w, proj_b,
                CC*HH*WW, WW, 1, HH*WW);
        k_mlp_s<<<dim3(NTOK/4), blk, 0, stream>>>(out,
                norm2_w, norm2_b, mlp_w1, mlp_b1, mlp_w2, mlp_b2,
                CC*HH*WW, 1, HH*WW);
    }
}